// Round 8
// baseline (161.212 us; speedup 1.0000x reference)
//
#include <hip/hip_runtime.h>
#include <stdint.h>

typedef unsigned short u16;
typedef unsigned int u32;
typedef __attribute__((ext_vector_type(8))) short short8;
typedef __attribute__((ext_vector_type(4))) float floatx4;

__device__ __forceinline__ u16 f2b(float f) {
    u32 u = __builtin_bit_cast(u32, f);
    return (u16)((u + 0x7fffu + ((u >> 16) & 1u)) >> 16);
}

__device__ __forceinline__ void gld16(const void* g, void* l) {
    __builtin_amdgcn_global_load_lds(
        (const __attribute__((address_space(1))) u32*)g,
        (__attribute__((address_space(3))) u32*)l, 16, 0, 0);
}

// raw barrier fenced against memory-op reordering (gld16 / ds_read must not cross)
#define BARM() { asm volatile("" ::: "memory"); __builtin_amdgcn_s_barrier(); asm volatile("" ::: "memory"); }
#define VMCNT(n) asm volatile("s_waitcnt vmcnt(" #n ")" ::: "memory")

// ---- merged prep (single-pass, 64KB LDS): blocks 0..511 = row norms +
// dual-layout Y (16 rows each); 512..767 = W^T. ----
__global__ __launch_bounds__(256) void prep_all(
    const float* __restrict__ x, const float* __restrict__ wgt,
    u16* __restrict__ YT, u16* __restrict__ Yn, u16* __restrict__ Wt) {
    __shared__ __align__(16) float sh[16 * 1024];   // 64 KB
    int b = blockIdx.x;
    int t = threadIdx.x;
    if (b < 512) {
        int r0 = b * 16;
        int tg = t >> 5, tl = t & 31;
        float ss[2] = {0.f, 0.f};
        for (int c = 0; c < 8; c++) {
            #pragma unroll
            for (int i = 0; i < 2; i++) {
                int row = i * 8 + tg;
                int col = c * 128 + tl * 4;
                float4 v = *(const float4*)(x + (long)(r0 + row) * 1024 + col);
                ss[i] += v.x * v.x + v.y * v.y + v.z * v.z + v.w * v.w;
                *(float4*)&sh[row * 1024 + (col ^ (row & 12))] = v;
            }
        }
        float sr_[2];
        #pragma unroll
        for (int i = 0; i < 2; i++) {
            #pragma unroll
            for (int m = 16; m > 0; m >>= 1) ss[i] += __shfl_xor(ss[i], m);
            float rcp = 1.0f / fmaxf(sqrtf(ss[i]), 1e-12f);
            sr_[i] = sqrtf(rcp);
        }
        for (int c = 0; c < 8; c++) {
            #pragma unroll
            for (int i = 0; i < 2; i++) {
                int row = i * 8 + tg;
                int col = c * 128 + tl * 4;
                float* p = &sh[row * 1024 + (col ^ (row & 12))];
                float4 v = *(float4*)p;
                v.x *= sr_[i]; v.y *= sr_[i]; v.z *= sr_[i]; v.w *= sr_[i];
                *(float4*)p = v;
                ushort4 o;
                o.x = f2b(v.x * sr_[i]); o.y = f2b(v.y * sr_[i]);
                o.z = f2b(v.z * sr_[i]); o.w = f2b(v.w * sr_[i]);
                *(ushort4*)(Yn + (long)(r0 + row) * 1024 + col) = o;
            }
        }
        __syncthreads();
        #pragma unroll
        for (int it = 0; it < 16; it++) {
            int lin = it * 256 + t;
            int cc = lin >> 2;
            int r4 = (lin & 3) << 2;
            ushort4 o;
            o.x = f2b(sh[(r4 + 0) * 1024 + (cc ^ r4)]);
            o.y = f2b(sh[(r4 + 1) * 1024 + (cc ^ r4)]);
            o.z = f2b(sh[(r4 + 2) * 1024 + (cc ^ r4)]);
            o.w = f2b(sh[(r4 + 3) * 1024 + (cc ^ r4)]);
            *(ushort4*)(YT + (long)cc * 8192 + r0 + r4) = o;
        }
    } else {
        float (*tile)[65] = (float(*)[65])sh;
        int bb = b - 512;
        int r0 = (bb >> 4) * 64, c0 = (bb & 15) * 64;
        #pragma unroll
        for (int i = 0; i < 4; i++) {
            int lin = i * 256 + t;
            int rr = lin >> 4, c4 = (lin & 15) << 2;
            float4 v = *(const float4*)(wgt + (long)(r0 + rr) * 1024 + c0 + c4);
            tile[rr][c4] = v.x; tile[rr][c4 + 1] = v.y;
            tile[rr][c4 + 2] = v.z; tile[rr][c4 + 3] = v.w;
        }
        __syncthreads();
        #pragma unroll
        for (int i = 0; i < 4; i++) {
            int lin = i * 256 + t;
            int cc = lin >> 4, r4 = (lin & 15) << 2;
            ushort4 o;
            o.x = f2b(tile[r4][cc]);
            o.y = f2b(tile[r4 + 1][cc]);
            o.z = f2b(tile[r4 + 2][cc]);
            o.w = f2b(tile[r4 + 3][cc]);
            *(ushort4*)(Wt + (long)(c0 + cc) * 1024 + r0 + r4) = o;
        }
    }
}

// ---- symmetric reduce for G (64x64 tiles, ti<=2*(tj>>1)+1 computed) ----
__global__ __launch_bounds__(256) void reduce_symC(
    const float* __restrict__ P, u16* __restrict__ D, int S, long E) {
    __shared__ float lt[64][65];
    int ti = blockIdx.x >> 4, tj = blockIdx.x & 15;
    if (ti > 2 * (tj >> 1) + 1) return;
    int mir = (tj > 2 * (ti >> 1) + 1);
    int t = threadIdx.x;
    int r = t >> 4, c4 = (t & 15) << 2;
    #pragma unroll
    for (int it = 0; it < 4; it++) {
        int row = it * 16 + r;
        long idx = (long)(64 * ti + row) * 1024 + 64 * tj + c4;
        float4 s = *(const float4*)(P + idx);
        for (int z = 1; z < S; z++) {
            float4 v = *(const float4*)(P + (long)z * E + idx);
            s.x += v.x; s.y += v.y; s.z += v.z; s.w += v.w;
        }
        ushort4 o; o.x = f2b(s.x); o.y = f2b(s.y); o.z = f2b(s.z); o.w = f2b(s.w);
        *(ushort4*)(D + idx) = o;
        if (mir) {
            lt[row][c4] = s.x; lt[row][c4 + 1] = s.y;
            lt[row][c4 + 2] = s.z; lt[row][c4 + 3] = s.w;
        }
    }
    if (mir) {
        __syncthreads();
        #pragma unroll
        for (int it = 0; it < 4; it++) {
            int dr = it * 16 + r;
            ushort4 o;
            o.x = f2b(lt[c4 + 0][dr]); o.y = f2b(lt[c4 + 1][dr]);
            o.z = f2b(lt[c4 + 2][dr]); o.w = f2b(lt[c4 + 3][dr]);
            *(ushort4*)(D + (long)(64 * tj + dr) * 1024 + 64 * ti + c4) = o;
        }
    }
}

// ---- reduce S split-K slabs of E fp32 each -> bf16 (plain) ----
__global__ __launch_bounds__(256) void reduce_cast(
    const float* __restrict__ P, u16* __restrict__ D, int S, long E) {
    long i = ((long)blockIdx.x * 256 + threadIdx.x) * 4;
    float4 s = *(const float4*)(P + i);
    for (int z = 1; z < S; z++) {
        float4 v = *(const float4*)(P + z * E + i);
        s.x += v.x; s.y += v.y; s.z += v.z; s.w += v.w;
    }
    ushort4 o;
    o.x = f2b(s.x); o.y = f2b(s.y); o.z = f2b(s.z); o.w = f2b(s.w);
    *(ushort4*)(D + i) = o;
}

// ---- GEMM 64(M)x128(N), BK=64, counted-vmcnt double-buffer (T4) ----
__global__ __launch_bounds__(256, 3) void gemm64x128(
    const u16* __restrict__ A, const u16* __restrict__ B,
    float* __restrict__ C, const float* __restrict__ rowscale,
    int lda, int ldb, int ldc, int tilesN, int kIters, long coffz, int sym, int obf16) {
    __shared__ __align__(16) u16 As[2][64 * 64];    // 2x8 KB
    __shared__ __align__(16) u16 Bs[2][128 * 64];   // 2x16 KB
    int bid = blockIdx.x;
    int nx = gridDim.x;
    if ((nx & 7) == 0) { int cpx = nx >> 3; bid = (bid & 7) * cpx + (bid >> 3); }
    int tm, tn;
    if (sym) {
        int id = bid, j = 0;
        while (true) {
            int c = (2 * j + 2 < 16) ? (2 * j + 2) : 16;
            if (id < c) break;
            id -= c; j++;
        }
        tn = j; tm = id;
    } else {
        tm = bid / tilesN; tn = bid % tilesN;
    }
    long kOff = (long)blockIdx.y * kIters * 64;
    const u16* Ap = A + (long)tm * 64 * lda + kOff;
    const u16* Bp = B + (long)tn * 128 * ldb + kOff;
    long coff = (long)blockIdx.y * coffz;

    int t = threadIdx.x;
    int lane = t & 63, w = t >> 6;
    int wm = (w & 1) * 32, wn = (w >> 1) * 64;
    int r16 = lane & 15, q = lane >> 4;

    int acl[2], bcl[4];
    #pragma unroll
    for (int j = 0; j < 2; j++) acl[j] = (w * 2 + j) * 64 + lane;
    #pragma unroll
    for (int j = 0; j < 4; j++) bcl[j] = (w * 4 + j) * 64 + lane;

    floatx4 acc[2][4];
    #pragma unroll
    for (int i = 0; i < 2; i++)
        #pragma unroll
        for (int j = 0; j < 4; j++) acc[i][j] = (floatx4){0.f, 0.f, 0.f, 0.f};

    #define STAGE64(buf, kt)                                                    \
        {                                                                       \
            long kk = (long)(kt) * 64;                                          \
            _Pragma("unroll")                                                   \
            for (int j = 0; j < 2; j++) {                                       \
                int cl = acl[j], row = cl >> 3, cg = (cl & 7) ^ (row & 7);      \
                gld16(Ap + (long)row * lda + kk + cg * 8, (void*)&As[buf][cl * 8]); \
            }                                                                   \
            _Pragma("unroll")                                                   \
            for (int j = 0; j < 4; j++) {                                       \
                int cl = bcl[j], row = cl >> 3, cg = (cl & 7) ^ (row & 7);      \
                gld16(Bp + (long)row * ldb + kk + cg * 8, (void*)&Bs[buf][cl * 8]); \
            }                                                                   \
        }

    #define COMPUTE64(buf)                                                      \
        {                                                                       \
            _Pragma("unroll")                                                   \
            for (int ks = 0; ks < 2; ks++) {                                    \
                short8 a[2], b[4];                                              \
                _Pragma("unroll")                                               \
                for (int i = 0; i < 2; i++) {                                   \
                    int rr = wm + i * 16 + r16;                                 \
                    int cc = (ks * 4 + q) ^ (rr & 7);                           \
                    a[i] = *(const short8*)&As[buf][rr * 64 + cc * 8];          \
                }                                                               \
                _Pragma("unroll")                                               \
                for (int j = 0; j < 4; j++) {                                   \
                    int rr = wn + j * 16 + r16;                                 \
                    int cc = (ks * 4 + q) ^ (rr & 7);                           \
                    b[j] = *(const short8*)&Bs[buf][rr * 64 + cc * 8];          \
                }                                                               \
                _Pragma("unroll")                                               \
                for (int i = 0; i < 2; i++)                                     \
                    _Pragma("unroll")                                           \
                    for (int j = 0; j < 4; j++)                                 \
                        acc[i][j] = __builtin_amdgcn_mfma_f32_16x16x32_bf16(    \
                            a[i], b[j], acc[i][j], 0, 0, 0);                    \
            }                                                                   \
        }

    STAGE64(0, 0);
    STAGE64(1, 1);
    VMCNT(6);
    BARM();
    int cur = 0;
    for (int kt = 0; kt < kIters - 2; kt++) {
        COMPUTE64(cur);
        BARM();
        STAGE64(cur, kt + 2);
        VMCNT(6);
        BARM();
        cur ^= 1;
    }
    COMPUTE64(cur);
    VMCNT(0);
    BARM();
    COMPUTE64(cur ^ 1);

    int m0 = tm * 64 + wm, n0 = tn * 128 + wn;
    #pragma unroll
    for (int i = 0; i < 2; i++) {
        int mm = m0 + i * 16 + q * 4;
        float rs[4];
        #pragma unroll
        for (int r = 0; r < 4; r++) rs[r] = (rowscale != nullptr) ? rowscale[mm + r] : 1.0f;
        #pragma unroll
        for (int j = 0; j < 4; j++) {
            int nn = n0 + j * 16 + r16;
            #pragma unroll
            for (int r = 0; r < 4; r++) {
                float v = acc[i][j][r] * rs[r];
                if (obf16) ((u16*)C)[coff + (long)(mm + r) * ldc + nn] = f2b(v);
                else       C[coff + (long)(mm + r) * ldc + nn] = v;
            }
        }
    }
    #undef STAGE64
    #undef COMPUTE64
}

// ---- GEMM 256(M)x128(N), BK=64 (stage 5): 4 waves each own 128x64
// (acc[8][4] -> 0.375 KB LDS per MFMA, the best fragment-reuse ratio at
// 4 waves). 96KB dbuf LDS, 1 block/CU, grid 32x8=256 = exact CU fill.
// Counted-vmcnt pipeline (12 loads/thread/tile), XOR-swizzled LDS. ----
__global__ __launch_bounds__(256, 1) void gemm256x128(
    const u16* __restrict__ A, const u16* __restrict__ B,
    float* __restrict__ C, int lda, int ldb, int ldc, int tilesN, int kIters) {
    __shared__ __align__(16) u16 As[2][256 * 64];   // 2x32 KB
    __shared__ __align__(16) u16 Bs[2][128 * 64];   // 2x16 KB
    int bid = blockIdx.x;
    int nx = gridDim.x;
    if ((nx & 7) == 0) { int cpx = nx >> 3; bid = (bid & 7) * cpx + (bid >> 3); }
    int tm = bid / tilesN, tn = bid % tilesN;
    const u16* Ap = A + (long)tm * 256 * lda;
    const u16* Bp = B + (long)tn * 128 * ldb;

    int t = threadIdx.x;
    int lane = t & 63, w = t >> 6;
    int wm = (w & 1) * 128, wn = (w >> 1) * 64;   // 2x2 waves of 128M x 64N
    int r16 = lane & 15, q = lane >> 4;

    floatx4 acc[8][4];
    #pragma unroll
    for (int i = 0; i < 8; i++)
        #pragma unroll
        for (int j = 0; j < 4; j++) acc[i][j] = (floatx4){0.f, 0.f, 0.f, 0.f};

    #define STAGE256(buf, kt)                                                   \
        {                                                                       \
            long kk = (long)(kt) * 64;                                          \
            _Pragma("unroll")                                                   \
            for (int j = 0; j < 8; j++) {   /* A: 256 rows x 8 chunks = 2048 */ \
                int cl = j * 256 + t, row = cl >> 3, cg = (cl & 7) ^ (row & 7); \
                gld16(Ap + (long)row * lda + kk + cg * 8, (void*)&As[buf][cl * 8]); \
            }                                                                   \
            _Pragma("unroll")                                                   \
            for (int j = 0; j < 4; j++) {   /* B: 128 rows x 8 chunks = 1024 */ \
                int cl = j * 256 + t, row = cl >> 3, cg = (cl & 7) ^ (row & 7); \
                gld16(Bp + (long)row * ldb + kk + cg * 8, (void*)&Bs[buf][cl * 8]); \
            }                                                                   \
        }

    #define COMPUTE256(buf)                                                     \
        {                                                                       \
            _Pragma("unroll")                                                   \
            for (int ks = 0; ks < 2; ks++) {                                    \
                short8 a[8], b[4];                                              \
                _Pragma("unroll")                                               \
                for (int i = 0; i < 8; i++) {                                   \
                    int rr = wm + i * 16 + r16;                                 \
                    int cc = (ks * 4 + q) ^ (rr & 7);                           \
                    a[i] = *(const short8*)&As[buf][rr * 64 + cc * 8];          \
                }                                                               \
                _Pragma("unroll")                                               \
                for (int j = 0; j < 4; j++) {                                   \
                    int rr = wn + j * 16 + r16;                                 \
                    int cc = (ks * 4 + q) ^ (rr & 7);                           \
                    b[j] = *(const short8*)&Bs[buf][rr * 64 + cc * 8];          \
                }                                                               \
                _Pragma("unroll")                                               \
                for (int i = 0; i < 8; i++)                                     \
                    _Pragma("unroll")                                           \
                    for (int j = 0; j < 4; j++)                                 \
                        acc[i][j] = __builtin_amdgcn_mfma_f32_16x16x32_bf16(    \
                            a[i], b[j], acc[i][j], 0, 0, 0);                    \
            }                                                                   \
        }

    STAGE256(0, 0);
    STAGE256(1, 1);
    VMCNT(12);
    BARM();
    int cur = 0;
    for (int kt = 0; kt < kIters - 2; kt++) {
        COMPUTE256(cur);
        BARM();
        STAGE256(cur, kt + 2);
        VMCNT(12);
        BARM();
        cur ^= 1;
    }
    COMPUTE256(cur);
    VMCNT(0);
    BARM();
    COMPUTE256(cur ^ 1);

    int m0 = tm * 256 + wm, n0 = tn * 128 + wn;
    #pragma unroll
    for (int i = 0; i < 8; i++) {
        int mm = m0 + i * 16 + q * 4;
        #pragma unroll
        for (int j = 0; j < 4; j++) {
            int nn = n0 + j * 16 + r16;
            #pragma unroll
            for (int r = 0; r < 4; r++)
                C[(long)(mm + r) * ldc + nn] = acc[i][j][r];
        }
    }
    #undef STAGE256
    #undef COMPUTE256
}

extern "C" void kernel_launch(void* const* d_in, const int* in_sizes, int n_in,
                              void* d_out, int out_size, void* d_ws, size_t ws_size,
                              hipStream_t stream) {
    const float* x = (const float*)d_in[0];
    const float* wgt = (const float*)d_in[1];
    float* out = (float*)d_out;
    char* ws = (char*)d_ws;

    const size_t MB = 1048576;
    u16*   YT = (u16*)ws;                  // 16 MB  Y^T = (diag(sqrt r)x)^T [1024][8192]
    u16*   Yn = (u16*)(ws + 16 * MB);      // 16 MB  diag(r)x row-major [8192][1024]
    u16*   Wt = (u16*)(ws + 32 * MB);      //  2 MB  W^T bf16
    u16*   Gb = (u16*)(ws + 34 * MB);      //  2 MB  G bf16
    u16*   Mt = (u16*)(ws + 36 * MB);      //  2 MB  M^T bf16
    float* Gp = (float*)(ws + 38 * MB);    // 32 MB  8x4MB G partials
    float* Mp = (float*)(ws + 70 * MB);    //  8 MB  2x4MB M^T partials
    // total 78 MB

    // 1) fused single-pass: row norms + Y^T + Yn (blocks 0..511) + W^T (512..767)
    prep_all<<<768, 256, 0, stream>>>(x, wgt, YT, Yn, Wt);
    // 2) G = Y^T·Y, upper-tri tiles (72 of 128 in 16x8 grid), split-K=8 -> Gp
    gemm64x128<<<dim3(72, 8), 256, 0, stream>>>(YT, YT, Gp, nullptr,
                                                8192, 8192, 1024, 8, 16, 1048576, 1, 0);
    // 3) Gb = bf16(sum Gp), mirroring the lower triangle (read-once)
    reduce_symC<<<256, 256, 0, stream>>>(Gp, Gb, 8, 1048576);
    // 4) M^T = W^T·G (G symmetric), split-K=2 (256 balanced blocks) -> Mp
    gemm64x128<<<dim3(128, 2), 256, 0, stream>>>(Wt, Gb, Mp, nullptr,
                                                 1024, 1024, 1024, 8, 8, 1048576, 0, 0);
    // 5) Mt = bf16(sum Mp)
    reduce_cast<<<1024, 256, 0, stream>>>(Mp, Mt, 2, 1048576);
    // 6) out = Yn·M  (M=8192, N=1024, K=1024; 32x8 = 256 blocks, 1/CU)
    gemm256x128<<<dim3(256, 1), 256, 0, stream>>>(Yn, Mt, out,
                                                  1024, 1024, 1024, 8, 16);
}

// Round 9
// 157.140 us; speedup vs baseline: 1.0259x; 1.0259x over previous
//
#include <hip/hip_runtime.h>
#include <stdint.h>

typedef unsigned short u16;
typedef unsigned int u32;
typedef __attribute__((ext_vector_type(8))) short short8;
typedef __attribute__((ext_vector_type(4))) float floatx4;

__device__ __forceinline__ u16 f2b(float f) {
    u32 u = __builtin_bit_cast(u32, f);
    return (u16)((u + 0x7fffu + ((u >> 16) & 1u)) >> 16);
}

__device__ __forceinline__ void gld16(const void* g, void* l) {
    __builtin_amdgcn_global_load_lds(
        (const __attribute__((address_space(1))) u32*)g,
        (__attribute__((address_space(3))) u32*)l, 16, 0, 0);
}

// raw barrier fenced against memory-op reordering (gld16 / ds_read must not cross)
#define BARM() { asm volatile("" ::: "memory"); __builtin_amdgcn_s_barrier(); asm volatile("" ::: "memory"); }
#define VMCNT(n) asm volatile("s_waitcnt vmcnt(" #n ")" ::: "memory")

// ---- merged prep (single-pass, 64KB LDS): blocks 0..511 = row norms +
// dual-layout Y (16 rows each); 512..767 = W^T. ----
__global__ __launch_bounds__(256) void prep_all(
    const float* __restrict__ x, const float* __restrict__ wgt,
    u16* __restrict__ YT, u16* __restrict__ Yn, u16* __restrict__ Wt) {
    __shared__ __align__(16) float sh[16 * 1024];   // 64 KB
    int b = blockIdx.x;
    int t = threadIdx.x;
    if (b < 512) {
        int r0 = b * 16;
        int tg = t >> 5, tl = t & 31;
        float ss[2] = {0.f, 0.f};
        for (int c = 0; c < 8; c++) {
            #pragma unroll
            for (int i = 0; i < 2; i++) {
                int row = i * 8 + tg;
                int col = c * 128 + tl * 4;
                float4 v = *(const float4*)(x + (long)(r0 + row) * 1024 + col);
                ss[i] += v.x * v.x + v.y * v.y + v.z * v.z + v.w * v.w;
                *(float4*)&sh[row * 1024 + (col ^ (row & 12))] = v;
            }
        }
        float sr_[2];
        #pragma unroll
        for (int i = 0; i < 2; i++) {
            #pragma unroll
            for (int m = 16; m > 0; m >>= 1) ss[i] += __shfl_xor(ss[i], m);
            float rcp = 1.0f / fmaxf(sqrtf(ss[i]), 1e-12f);
            sr_[i] = sqrtf(rcp);
        }
        for (int c = 0; c < 8; c++) {
            #pragma unroll
            for (int i = 0; i < 2; i++) {
                int row = i * 8 + tg;
                int col = c * 128 + tl * 4;
                float* p = &sh[row * 1024 + (col ^ (row & 12))];
                float4 v = *(float4*)p;
                v.x *= sr_[i]; v.y *= sr_[i]; v.z *= sr_[i]; v.w *= sr_[i];
                *(float4*)p = v;
                ushort4 o;
                o.x = f2b(v.x * sr_[i]); o.y = f2b(v.y * sr_[i]);
                o.z = f2b(v.z * sr_[i]); o.w = f2b(v.w * sr_[i]);
                *(ushort4*)(Yn + (long)(r0 + row) * 1024 + col) = o;
            }
        }
        __syncthreads();
        #pragma unroll
        for (int it = 0; it < 16; it++) {
            int lin = it * 256 + t;
            int cc = lin >> 2;
            int r4 = (lin & 3) << 2;
            ushort4 o;
            o.x = f2b(sh[(r4 + 0) * 1024 + (cc ^ r4)]);
            o.y = f2b(sh[(r4 + 1) * 1024 + (cc ^ r4)]);
            o.z = f2b(sh[(r4 + 2) * 1024 + (cc ^ r4)]);
            o.w = f2b(sh[(r4 + 3) * 1024 + (cc ^ r4)]);
            *(ushort4*)(YT + (long)cc * 8192 + r0 + r4) = o;
        }
    } else {
        float (*tile)[65] = (float(*)[65])sh;
        int bb = b - 512;
        int r0 = (bb >> 4) * 64, c0 = (bb & 15) * 64;
        #pragma unroll
        for (int i = 0; i < 4; i++) {
            int lin = i * 256 + t;
            int rr = lin >> 4, c4 = (lin & 15) << 2;
            float4 v = *(const float4*)(wgt + (long)(r0 + rr) * 1024 + c0 + c4);
            tile[rr][c4] = v.x; tile[rr][c4 + 1] = v.y;
            tile[rr][c4 + 2] = v.z; tile[rr][c4 + 3] = v.w;
        }
        __syncthreads();
        #pragma unroll
        for (int i = 0; i < 4; i++) {
            int lin = i * 256 + t;
            int cc = lin >> 4, r4 = (lin & 15) << 2;
            ushort4 o;
            o.x = f2b(tile[r4][cc]);
            o.y = f2b(tile[r4 + 1][cc]);
            o.z = f2b(tile[r4 + 2][cc]);
            o.w = f2b(tile[r4 + 3][cc]);
            *(ushort4*)(Wt + (long)(c0 + cc) * 1024 + r0 + r4) = o;
        }
    }
}

// ---- symmetric reduce for G: stage-2 now computes 128x128 tiles (TM<=TN),
// i.e. 64-granule (ti,tj) computed iff (ti>>1) <= (tj>>1). kept -> direct
// sum+write; if mirror (tj,ti) NOT computed ((tj>>1) > (ti>>1)), also write
// the transpose. Others exit. ----
__global__ __launch_bounds__(256) void reduce_symC(
    const float* __restrict__ P, u16* __restrict__ D, int S, long E) {
    __shared__ float lt[64][65];
    int ti = blockIdx.x >> 4, tj = blockIdx.x & 15;
    if ((ti >> 1) > (tj >> 1)) return;                // not computed
    int mir = ((tj >> 1) > (ti >> 1));                // mirror not computed
    int t = threadIdx.x;
    int r = t >> 4, c4 = (t & 15) << 2;
    #pragma unroll
    for (int it = 0; it < 4; it++) {
        int row = it * 16 + r;
        long idx = (long)(64 * ti + row) * 1024 + 64 * tj + c4;
        float4 s = *(const float4*)(P + idx);
        for (int z = 1; z < S; z++) {
            float4 v = *(const float4*)(P + (long)z * E + idx);
            s.x += v.x; s.y += v.y; s.z += v.z; s.w += v.w;
        }
        ushort4 o; o.x = f2b(s.x); o.y = f2b(s.y); o.z = f2b(s.z); o.w = f2b(s.w);
        *(ushort4*)(D + idx) = o;
        if (mir) {
            lt[row][c4] = s.x; lt[row][c4 + 1] = s.y;
            lt[row][c4 + 2] = s.z; lt[row][c4 + 3] = s.w;
        }
    }
    if (mir) {
        __syncthreads();
        #pragma unroll
        for (int it = 0; it < 4; it++) {
            int dr = it * 16 + r;
            ushort4 o;
            o.x = f2b(lt[c4 + 0][dr]); o.y = f2b(lt[c4 + 1][dr]);
            o.z = f2b(lt[c4 + 2][dr]); o.w = f2b(lt[c4 + 3][dr]);
            *(ushort4*)(D + (long)(64 * tj + dr) * 1024 + 64 * ti + c4) = o;
        }
    }
}

// ---- GEMM 64(M)x128(N), BK=64, counted-vmcnt double-buffer (T4) ----
// (stage 4 only: W^T·G, 128 blocks, bf16 out)
__global__ __launch_bounds__(256, 3) void gemm64x128(
    const u16* __restrict__ A, const u16* __restrict__ B,
    float* __restrict__ C, const float* __restrict__ rowscale,
    int lda, int ldb, int ldc, int tilesN, int kIters, long coffz, int sym, int obf16) {
    __shared__ __align__(16) u16 As[2][64 * 64];    // 2x8 KB
    __shared__ __align__(16) u16 Bs[2][128 * 64];   // 2x16 KB
    int bid = blockIdx.x;
    int nx = gridDim.x;
    if ((nx & 7) == 0) { int cpx = nx >> 3; bid = (bid & 7) * cpx + (bid >> 3); }
    int tm, tn;
    if (sym) {
        int id = bid, j = 0;
        while (true) {
            int c = (2 * j + 2 < 16) ? (2 * j + 2) : 16;
            if (id < c) break;
            id -= c; j++;
        }
        tn = j; tm = id;
    } else {
        tm = bid / tilesN; tn = bid % tilesN;
    }
    long kOff = (long)blockIdx.y * kIters * 64;
    const u16* Ap = A + (long)tm * 64 * lda + kOff;
    const u16* Bp = B + (long)tn * 128 * ldb + kOff;
    long coff = (long)blockIdx.y * coffz;

    int t = threadIdx.x;
    int lane = t & 63, w = t >> 6;
    int wm = (w & 1) * 32, wn = (w >> 1) * 64;
    int r16 = lane & 15, q = lane >> 4;

    int acl[2], bcl[4];
    #pragma unroll
    for (int j = 0; j < 2; j++) acl[j] = (w * 2 + j) * 64 + lane;
    #pragma unroll
    for (int j = 0; j < 4; j++) bcl[j] = (w * 4 + j) * 64 + lane;

    floatx4 acc[2][4];
    #pragma unroll
    for (int i = 0; i < 2; i++)
        #pragma unroll
        for (int j = 0; j < 4; j++) acc[i][j] = (floatx4){0.f, 0.f, 0.f, 0.f};

    #define STAGE64(buf, kt)                                                    \
        {                                                                       \
            long kk = (long)(kt) * 64;                                          \
            _Pragma("unroll")                                                   \
            for (int j = 0; j < 2; j++) {                                       \
                int cl = acl[j], row = cl >> 3, cg = (cl & 7) ^ (row & 7);      \
                gld16(Ap + (long)row * lda + kk + cg * 8, (void*)&As[buf][cl * 8]); \
            }                                                                   \
            _Pragma("unroll")                                                   \
            for (int j = 0; j < 4; j++) {                                       \
                int cl = bcl[j], row = cl >> 3, cg = (cl & 7) ^ (row & 7);      \
                gld16(Bp + (long)row * ldb + kk + cg * 8, (void*)&Bs[buf][cl * 8]); \
            }                                                                   \
        }

    #define COMPUTE64(buf)                                                      \
        {                                                                       \
            _Pragma("unroll")                                                   \
            for (int ks = 0; ks < 2; ks++) {                                    \
                short8 a[2], b[4];                                              \
                _Pragma("unroll")                                               \
                for (int i = 0; i < 2; i++) {                                   \
                    int rr = wm + i * 16 + r16;                                 \
                    int cc = (ks * 4 + q) ^ (rr & 7);                           \
                    a[i] = *(const short8*)&As[buf][rr * 64 + cc * 8];          \
                }                                                               \
                _Pragma("unroll")                                               \
                for (int j = 0; j < 4; j++) {                                   \
                    int rr = wn + j * 16 + r16;                                 \
                    int cc = (ks * 4 + q) ^ (rr & 7);                           \
                    b[j] = *(const short8*)&Bs[buf][rr * 64 + cc * 8];          \
                }                                                               \
                _Pragma("unroll")                                               \
                for (int i = 0; i < 2; i++)                                     \
                    _Pragma("unroll")                                           \
                    for (int j = 0; j < 4; j++)                                 \
                        acc[i][j] = __builtin_amdgcn_mfma_f32_16x16x32_bf16(    \
                            a[i], b[j], acc[i][j], 0, 0, 0);                    \
            }                                                                   \
        }

    STAGE64(0, 0);
    STAGE64(1, 1);
    VMCNT(6);
    BARM();
    int cur = 0;
    for (int kt = 0; kt < kIters - 2; kt++) {
        COMPUTE64(cur);
        BARM();
        STAGE64(cur, kt + 2);
        VMCNT(6);
        BARM();
        cur ^= 1;
    }
    COMPUTE64(cur);
    VMCNT(0);
    BARM();
    COMPUTE64(cur ^ 1);

    int m0 = tm * 64 + wm, n0 = tn * 128 + wn;
    #pragma unroll
    for (int i = 0; i < 2; i++) {
        int mm = m0 + i * 16 + q * 4;
        float rs[4];
        #pragma unroll
        for (int r = 0; r < 4; r++) rs[r] = (rowscale != nullptr) ? rowscale[mm + r] : 1.0f;
        #pragma unroll
        for (int j = 0; j < 4; j++) {
            int nn = n0 + j * 16 + r16;
            #pragma unroll
            for (int r = 0; r < 4; r++) {
                float v = acc[i][j][r] * rs[r];
                if (obf16) ((u16*)C)[coff + (long)(mm + r) * ldc + nn] = f2b(v);
                else       C[coff + (long)(mm + r) * ldc + nn] = v;
            }
        }
    }
    #undef STAGE64
    #undef COMPUTE64
}

// ---- GEMM 128x128, BK=64, counted-vmcnt double-buffer (2 blocks/CU) ----
// sym=1: grid.x=36 upper-tri tiles (tm<=tn) of an 8x8 tile grid (stage 2).
__global__ __launch_bounds__(256, 2) void gemm128(
    const u16* __restrict__ A, const u16* __restrict__ B,
    float* __restrict__ C, const float* __restrict__ rowscale,
    int lda, int ldb, int ldc, int tilesN, int kIters, long coffz, int sym) {
    __shared__ __align__(16) u16 As[2][128 * 64];   // 2x16 KB
    __shared__ __align__(16) u16 Bs[2][128 * 64];   // 2x16 KB
    int bid = blockIdx.x;
    int nx = gridDim.x;
    if ((nx & 7) == 0) { int cpx = nx >> 3; bid = (bid & 7) * cpx + (bid >> 3); }
    int tm, tn;
    if (sym) {
        int id = bid, j = 0;
        while (true) {
            int c = j + 1;
            if (id < c) break;
            id -= c; j++;
        }
        tn = j; tm = id;   // tm <= tn over 8x8
    } else {
        tm = bid / tilesN; tn = bid % tilesN;
    }
    long kOff = (long)blockIdx.y * kIters * 64;
    const u16* Ap = A + (long)tm * 128 * lda + kOff;
    const u16* Bp = B + (long)tn * 128 * ldb + kOff;
    long coff = (long)blockIdx.y * coffz;

    int t = threadIdx.x;
    int lane = t & 63, w = t >> 6;
    int wm = (w & 1) * 64, wn = (w >> 1) * 64;
    int r16 = lane & 15, q = lane >> 4;

    floatx4 acc[4][4];
    #pragma unroll
    for (int i = 0; i < 4; i++)
        #pragma unroll
        for (int j = 0; j < 4; j++) acc[i][j] = (floatx4){0.f, 0.f, 0.f, 0.f};

    #define STAGE128(buf, kt)                                                   \
        {                                                                       \
            long kk = (long)(kt) * 64;                                          \
            _Pragma("unroll")                                                   \
            for (int j = 0; j < 4; j++) {                                       \
                int cl = j * 256 + t, row = cl >> 3, cg = (cl & 7) ^ (row & 7); \
                gld16(Ap + (long)row * lda + kk + cg * 8, (void*)&As[buf][cl * 8]); \
            }                                                                   \
            _Pragma("unroll")                                                   \
            for (int j = 0; j < 4; j++) {                                       \
                int cl = j * 256 + t, row = cl >> 3, cg = (cl & 7) ^ (row & 7); \
                gld16(Bp + (long)row * ldb + kk + cg * 8, (void*)&Bs[buf][cl * 8]); \
            }                                                                   \
        }

    #define COMPUTE128(buf)                                                     \
        {                                                                       \
            _Pragma("unroll")                                                   \
            for (int ks = 0; ks < 2; ks++) {                                    \
                short8 a[4], b[4];                                              \
                _Pragma("unroll")                                               \
                for (int i = 0; i < 4; i++) {                                   \
                    int rr = wm + i * 16 + r16;                                 \
                    int cc = (ks * 4 + q) ^ (rr & 7);                           \
                    a[i] = *(const short8*)&As[buf][rr * 64 + cc * 8];          \
                }                                                               \
                _Pragma("unroll")                                               \
                for (int j = 0; j < 4; j++) {                                   \
                    int rr = wn + j * 16 + r16;                                 \
                    int cc = (ks * 4 + q) ^ (rr & 7);                           \
                    b[j] = *(const short8*)&Bs[buf][rr * 64 + cc * 8];          \
                }                                                               \
                _Pragma("unroll")                                               \
                for (int i = 0; i < 4; i++)                                     \
                    _Pragma("unroll")                                           \
                    for (int j = 0; j < 4; j++)                                 \
                        acc[i][j] = __builtin_amdgcn_mfma_f32_16x16x32_bf16(    \
                            a[i], b[j], acc[i][j], 0, 0, 0);                    \
            }                                                                   \
        }

    STAGE128(0, 0);
    STAGE128(1, 1);
    VMCNT(8);
    BARM();
    int cur = 0;
    for (int kt = 0; kt < kIters - 2; kt++) {
        COMPUTE128(cur);
        BARM();
        STAGE128(cur, kt + 2);
        VMCNT(8);
        BARM();
        cur ^= 1;
    }
    COMPUTE128(cur);
    VMCNT(0);
    BARM();
    COMPUTE128(cur ^ 1);

    int m0 = tm * 128 + wm, n0 = tn * 128 + wn;
    #pragma unroll
    for (int i = 0; i < 4; i++) {
        int mm = m0 + i * 16 + q * 4;
        float rs[4];
        #pragma unroll
        for (int r = 0; r < 4; r++) rs[r] = (rowscale != nullptr) ? rowscale[mm + r] : 1.0f;
        #pragma unroll
        for (int j = 0; j < 4; j++) {
            int nn = n0 + j * 16 + r16;
            #pragma unroll
            for (int r = 0; r < 4; r++)
                C[coff + (long)(mm + r) * ldc + nn] = acc[i][j][r] * rs[r];
        }
    }
    #undef STAGE128
    #undef COMPUTE128
}

extern "C" void kernel_launch(void* const* d_in, const int* in_sizes, int n_in,
                              void* d_out, int out_size, void* d_ws, size_t ws_size,
                              hipStream_t stream) {
    const float* x = (const float*)d_in[0];
    const float* wgt = (const float*)d_in[1];
    float* out = (float*)d_out;
    char* ws = (char*)d_ws;

    const size_t MB = 1048576;
    u16*   YT = (u16*)ws;                  // 16 MB  Y^T = (diag(sqrt r)x)^T [1024][8192]
    u16*   Yn = (u16*)(ws + 16 * MB);      // 16 MB  diag(r)x row-major [8192][1024]
    u16*   Wt = (u16*)(ws + 32 * MB);      //  2 MB  W^T bf16
    u16*   Gb = (u16*)(ws + 34 * MB);      //  2 MB  G bf16
    u16*   Mt = (u16*)(ws + 36 * MB);      //  2 MB  M^T bf16
    float* Gp = (float*)(ws + 38 * MB);    // 32 MB  8x4MB G partials
    // total 70 MB

    // 1) fused single-pass: row norms + Y^T + Yn (blocks 0..511) + W^T (512..767)
    prep_all<<<768, 256, 0, stream>>>(x, wgt, YT, Yn, Wt);
    // 2) G = Y^T·Y, 128x128 upper-tri tiles (36 of 64), split-K=8 -> Gp
    //    288 blocks at 2/CU: all resident, best LDS-read/MFMA ratio (0.5 KB/MFMA)
    gemm128<<<dim3(36, 8), 256, 0, stream>>>(YT, YT, Gp, nullptr,
                                             8192, 8192, 1024, 8, 16, 1048576, 1);
    // 3) Gb = bf16(sum Gp), mirroring the lower triangle (128^2-tri predicate)
    reduce_symC<<<256, 256, 0, stream>>>(Gp, Gb, 8, 1048576);
    // 4) M^T = W^T·G (G symmetric), no split-K, bf16 out -> Mt
    gemm64x128<<<dim3(128, 1), 256, 0, stream>>>(Wt, Gb, (float*)Mt, nullptr,
                                                 1024, 1024, 1024, 8, 16, 0, 0, 1);
    // 5) out = Yn·M  (M=8192, N=1024, K=1024, 512 blocks at 2/CU)
    gemm128<<<dim3(512, 1), 256, 0, stream>>>(Yn, Mt, out, nullptr,
                                              1024, 1024, 1024, 8, 16, 0, 0);
}

// Round 10
// 152.185 us; speedup vs baseline: 1.0593x; 1.0326x over previous
//
#include <hip/hip_runtime.h>
#include <stdint.h>

typedef unsigned short u16;
typedef unsigned int u32;
typedef __attribute__((ext_vector_type(8))) short short8;
typedef __attribute__((ext_vector_type(4))) float floatx4;

__device__ __forceinline__ u16 f2b(float f) {
    u32 u = __builtin_bit_cast(u32, f);
    return (u16)((u + 0x7fffu + ((u >> 16) & 1u)) >> 16);
}

__device__ __forceinline__ void gld16(const void* g, void* l) {
    __builtin_amdgcn_global_load_lds(
        (const __attribute__((address_space(1))) u32*)g,
        (__attribute__((address_space(3))) u32*)l, 16, 0, 0);
}

// raw barrier fenced against memory-op reordering (gld16 / ds_read must not cross)
#define BARM() { asm volatile("" ::: "memory"); __builtin_amdgcn_s_barrier(); asm volatile("" ::: "memory"); }
#define VMCNT(n) asm volatile("s_waitcnt vmcnt(" #n ")" ::: "memory")

// ---- merged prep (single-pass, 64KB LDS): blocks 0..511 = row norms +
// dual-layout Y (16 rows each); 512..767 = W^T. ----
__global__ __launch_bounds__(256) void prep_all(
    const float* __restrict__ x, const float* __restrict__ wgt,
    u16* __restrict__ YT, u16* __restrict__ Yn, u16* __restrict__ Wt) {
    __shared__ __align__(16) float sh[16 * 1024];   // 64 KB
    int b = blockIdx.x;
    int t = threadIdx.x;
    if (b < 512) {
        int r0 = b * 16;
        int tg = t >> 5, tl = t & 31;
        float ss[2] = {0.f, 0.f};
        for (int c = 0; c < 8; c++) {
            #pragma unroll
            for (int i = 0; i < 2; i++) {
                int row = i * 8 + tg;
                int col = c * 128 + tl * 4;
                float4 v = *(const float4*)(x + (long)(r0 + row) * 1024 + col);
                ss[i] += v.x * v.x + v.y * v.y + v.z * v.z + v.w * v.w;
                *(float4*)&sh[row * 1024 + (col ^ (row & 12))] = v;
            }
        }
        float sr_[2];
        #pragma unroll
        for (int i = 0; i < 2; i++) {
            #pragma unroll
            for (int m = 16; m > 0; m >>= 1) ss[i] += __shfl_xor(ss[i], m);
            float rcp = 1.0f / fmaxf(sqrtf(ss[i]), 1e-12f);
            sr_[i] = sqrtf(rcp);
        }
        for (int c = 0; c < 8; c++) {
            #pragma unroll
            for (int i = 0; i < 2; i++) {
                int row = i * 8 + tg;
                int col = c * 128 + tl * 4;
                float* p = &sh[row * 1024 + (col ^ (row & 12))];
                float4 v = *(float4*)p;
                v.x *= sr_[i]; v.y *= sr_[i]; v.z *= sr_[i]; v.w *= sr_[i];
                *(float4*)p = v;
                ushort4 o;
                o.x = f2b(v.x * sr_[i]); o.y = f2b(v.y * sr_[i]);
                o.z = f2b(v.z * sr_[i]); o.w = f2b(v.w * sr_[i]);
                *(ushort4*)(Yn + (long)(r0 + row) * 1024 + col) = o;
            }
        }
        __syncthreads();
        #pragma unroll
        for (int it = 0; it < 16; it++) {
            int lin = it * 256 + t;
            int cc = lin >> 2;
            int r4 = (lin & 3) << 2;
            ushort4 o;
            o.x = f2b(sh[(r4 + 0) * 1024 + (cc ^ r4)]);
            o.y = f2b(sh[(r4 + 1) * 1024 + (cc ^ r4)]);
            o.z = f2b(sh[(r4 + 2) * 1024 + (cc ^ r4)]);
            o.w = f2b(sh[(r4 + 3) * 1024 + (cc ^ r4)]);
            *(ushort4*)(YT + (long)cc * 8192 + r0 + r4) = o;
        }
    } else {
        float (*tile)[65] = (float(*)[65])sh;
        int bb = b - 512;
        int r0 = (bb >> 4) * 64, c0 = (bb & 15) * 64;
        #pragma unroll
        for (int i = 0; i < 4; i++) {
            int lin = i * 256 + t;
            int rr = lin >> 4, c4 = (lin & 15) << 2;
            float4 v = *(const float4*)(wgt + (long)(r0 + rr) * 1024 + c0 + c4);
            tile[rr][c4] = v.x; tile[rr][c4 + 1] = v.y;
            tile[rr][c4 + 2] = v.z; tile[rr][c4 + 3] = v.w;
        }
        __syncthreads();
        #pragma unroll
        for (int i = 0; i < 4; i++) {
            int lin = i * 256 + t;
            int cc = lin >> 4, r4 = (lin & 15) << 2;
            ushort4 o;
            o.x = f2b(tile[r4][cc]);
            o.y = f2b(tile[r4 + 1][cc]);
            o.z = f2b(tile[r4 + 2][cc]);
            o.w = f2b(tile[r4 + 3][cc]);
            *(ushort4*)(Wt + (long)(c0 + cc) * 1024 + r0 + r4) = o;
        }
    }
}

// ---- symmetric reduce for G: stage-2 computed 64x64 tiles (ti,tj) iff
// ti <= 2*(tj>>1)+1 (64x128 tiling, tm<=2*tn+1). kept -> direct sum+write;
// if mirror (tj,ti) NOT computed, also write the transpose. ----
__global__ __launch_bounds__(256) void reduce_symC(
    const float* __restrict__ P, u16* __restrict__ D, int S, long E) {
    __shared__ float lt[64][65];
    int ti = blockIdx.x >> 4, tj = blockIdx.x & 15;
    if (ti > 2 * (tj >> 1) + 1) return;               // not computed
    int mir = (tj > 2 * (ti >> 1) + 1);               // mirror not computed
    int t = threadIdx.x;
    int r = t >> 4, c4 = (t & 15) << 2;
    #pragma unroll
    for (int it = 0; it < 4; it++) {
        int row = it * 16 + r;
        long idx = (long)(64 * ti + row) * 1024 + 64 * tj + c4;
        float4 s = *(const float4*)(P + idx);
        for (int z = 1; z < S; z++) {
            float4 v = *(const float4*)(P + (long)z * E + idx);
            s.x += v.x; s.y += v.y; s.z += v.z; s.w += v.w;
        }
        ushort4 o; o.x = f2b(s.x); o.y = f2b(s.y); o.z = f2b(s.z); o.w = f2b(s.w);
        *(ushort4*)(D + idx) = o;
        if (mir) {
            lt[row][c4] = s.x; lt[row][c4 + 1] = s.y;
            lt[row][c4 + 2] = s.z; lt[row][c4 + 3] = s.w;
        }
    }
    if (mir) {
        __syncthreads();
        #pragma unroll
        for (int it = 0; it < 4; it++) {
            int dr = it * 16 + r;
            ushort4 o;
            o.x = f2b(lt[c4 + 0][dr]); o.y = f2b(lt[c4 + 1][dr]);
            o.z = f2b(lt[c4 + 2][dr]); o.w = f2b(lt[c4 + 3][dr]);
            *(ushort4*)(D + (long)(64 * tj + dr) * 1024 + 64 * ti + c4) = o;
        }
    }
}

// ---- GEMM 64(M)x128(N), BK=64, counted-vmcnt double-buffer (T4) ----
// Per K-step: COMPUTE(cur) -> BAR -> STAGE(cur, kt+2) -> vmcnt(6)+BAR.
// 48KB LDS -> 3 blocks/CU. XOR-swizzled LDS, conflict-free ds_read_b128.
// sym=1: grid.x=72 tiles (tm<=2*tn+1) of a 16x8 tile grid. obf16: bf16 C.
__global__ __launch_bounds__(256, 3) void gemm64x128(
    const u16* __restrict__ A, const u16* __restrict__ B,
    float* __restrict__ C, const float* __restrict__ rowscale,
    int lda, int ldb, int ldc, int tilesN, int kIters, long coffz, int sym, int obf16) {
    __shared__ __align__(16) u16 As[2][64 * 64];    // 2x8 KB
    __shared__ __align__(16) u16 Bs[2][128 * 64];   // 2x16 KB
    int bid = blockIdx.x;
    int nx = gridDim.x;
    if ((nx & 7) == 0) { int cpx = nx >> 3; bid = (bid & 7) * cpx + (bid >> 3); }
    int tm, tn;
    if (sym) {
        int id = bid, j = 0;
        while (true) {
            int c = (2 * j + 2 < 16) ? (2 * j + 2) : 16;
            if (id < c) break;
            id -= c; j++;
        }
        tn = j; tm = id;
    } else {
        tm = bid / tilesN; tn = bid % tilesN;
    }
    long kOff = (long)blockIdx.y * kIters * 64;
    const u16* Ap = A + (long)tm * 64 * lda + kOff;
    const u16* Bp = B + (long)tn * 128 * ldb + kOff;
    long coff = (long)blockIdx.y * coffz;

    int t = threadIdx.x;
    int lane = t & 63, w = t >> 6;
    int wm = (w & 1) * 32, wn = (w >> 1) * 64;
    int r16 = lane & 15, q = lane >> 4;

    int acl[2], bcl[4];
    #pragma unroll
    for (int j = 0; j < 2; j++) acl[j] = (w * 2 + j) * 64 + lane;
    #pragma unroll
    for (int j = 0; j < 4; j++) bcl[j] = (w * 4 + j) * 64 + lane;

    floatx4 acc[2][4];
    #pragma unroll
    for (int i = 0; i < 2; i++)
        #pragma unroll
        for (int j = 0; j < 4; j++) acc[i][j] = (floatx4){0.f, 0.f, 0.f, 0.f};

    #define STAGE64(buf, kt)                                                    \
        {                                                                       \
            long kk = (long)(kt) * 64;                                          \
            _Pragma("unroll")                                                   \
            for (int j = 0; j < 2; j++) {                                       \
                int cl = acl[j], row = cl >> 3, cg = (cl & 7) ^ (row & 7);      \
                gld16(Ap + (long)row * lda + kk + cg * 8, (void*)&As[buf][cl * 8]); \
            }                                                                   \
            _Pragma("unroll")                                                   \
            for (int j = 0; j < 4; j++) {                                       \
                int cl = bcl[j], row = cl >> 3, cg = (cl & 7) ^ (row & 7);      \
                gld16(Bp + (long)row * ldb + kk + cg * 8, (void*)&Bs[buf][cl * 8]); \
            }                                                                   \
        }

    #define COMPUTE64(buf)                                                      \
        {                                                                       \
            _Pragma("unroll")                                                   \
            for (int ks = 0; ks < 2; ks++) {                                    \
                short8 a[2], b[4];                                              \
                _Pragma("unroll")                                               \
                for (int i = 0; i < 2; i++) {                                   \
                    int rr = wm + i * 16 + r16;                                 \
                    int cc = (ks * 4 + q) ^ (rr & 7);                           \
                    a[i] = *(const short8*)&As[buf][rr * 64 + cc * 8];          \
                }                                                               \
                _Pragma("unroll")                                               \
                for (int j = 0; j < 4; j++) {                                   \
                    int rr = wn + j * 16 + r16;                                 \
                    int cc = (ks * 4 + q) ^ (rr & 7);                           \
                    b[j] = *(const short8*)&Bs[buf][rr * 64 + cc * 8];          \
                }                                                               \
                _Pragma("unroll")                                               \
                for (int i = 0; i < 2; i++)                                     \
                    _Pragma("unroll")                                           \
                    for (int j = 0; j < 4; j++)                                 \
                        acc[i][j] = __builtin_amdgcn_mfma_f32_16x16x32_bf16(    \
                            a[i], b[j], acc[i][j], 0, 0, 0);                    \
            }                                                                   \
        }

    STAGE64(0, 0);
    STAGE64(1, 1);
    VMCNT(6);
    BARM();
    int cur = 0;
    for (int kt = 0; kt < kIters - 2; kt++) {
        COMPUTE64(cur);
        BARM();
        STAGE64(cur, kt + 2);
        VMCNT(6);
        BARM();
        cur ^= 1;
    }
    COMPUTE64(cur);
    VMCNT(0);
    BARM();
    COMPUTE64(cur ^ 1);

    int m0 = tm * 64 + wm, n0 = tn * 128 + wn;
    #pragma unroll
    for (int i = 0; i < 2; i++) {
        int mm = m0 + i * 16 + q * 4;
        float rs[4];
        #pragma unroll
        for (int r = 0; r < 4; r++) rs[r] = (rowscale != nullptr) ? rowscale[mm + r] : 1.0f;
        #pragma unroll
        for (int j = 0; j < 4; j++) {
            int nn = n0 + j * 16 + r16;
            #pragma unroll
            for (int r = 0; r < 4; r++) {
                float v = acc[i][j][r] * rs[r];
                if (obf16) ((u16*)C)[coff + (long)(mm + r) * ldc + nn] = f2b(v);
                else       C[coff + (long)(mm + r) * ldc + nn] = v;
            }
        }
    }
    #undef STAGE64
    #undef COMPUTE64
}

// ---- GEMM 128x128, BK=64, counted-vmcnt double-buffer (2 blocks/CU) ----
__global__ __launch_bounds__(256, 2) void gemm128(
    const u16* __restrict__ A, const u16* __restrict__ B,
    float* __restrict__ C, const float* __restrict__ rowscale,
    int lda, int ldb, int ldc, int tilesN, int kIters) {
    __shared__ __align__(16) u16 As[2][128 * 64];   // 2x16 KB
    __shared__ __align__(16) u16 Bs[2][128 * 64];   // 2x16 KB
    int bid = blockIdx.x;
    int nx = gridDim.x;
    if ((nx & 7) == 0) { int cpx = nx >> 3; bid = (bid & 7) * cpx + (bid >> 3); }
    int tm = bid / tilesN, tn = bid % tilesN;
    const u16* Ap = A + (long)tm * 128 * lda;
    const u16* Bp = B + (long)tn * 128 * ldb;

    int t = threadIdx.x;
    int lane = t & 63, w = t >> 6;
    int wm = (w & 1) * 64, wn = (w >> 1) * 64;
    int r16 = lane & 15, q = lane >> 4;

    floatx4 acc[4][4];
    #pragma unroll
    for (int i = 0; i < 4; i++)
        #pragma unroll
        for (int j = 0; j < 4; j++) acc[i][j] = (floatx4){0.f, 0.f, 0.f, 0.f};

    #define STAGE128(buf, kt)                                                   \
        {                                                                       \
            long kk = (long)(kt) * 64;                                          \
            _Pragma("unroll")                                                   \
            for (int j = 0; j < 4; j++) {                                       \
                int cl = j * 256 + t, row = cl >> 3, cg = (cl & 7) ^ (row & 7); \
                gld16(Ap + (long)row * lda + kk + cg * 8, (void*)&As[buf][cl * 8]); \
            }                                                                   \
            _Pragma("unroll")                                                   \
            for (int j = 0; j < 4; j++) {                                       \
                int cl = j * 256 + t, row = cl >> 3, cg = (cl & 7) ^ (row & 7); \
                gld16(Bp + (long)row * ldb + kk + cg * 8, (void*)&Bs[buf][cl * 8]); \
            }                                                                   \
        }

    #define COMPUTE128(buf)                                                     \
        {                                                                       \
            _Pragma("unroll")                                                   \
            for (int ks = 0; ks < 2; ks++) {                                    \
                short8 a[4], b[4];                                              \
                _Pragma("unroll")                                               \
                for (int i = 0; i < 4; i++) {                                   \
                    int rr = wm + i * 16 + r16;                                 \
                    int cc = (ks * 4 + q) ^ (rr & 7);                           \
                    a[i] = *(const short8*)&As[buf][rr * 64 + cc * 8];          \
                }                                                               \
                _Pragma("unroll")                                               \
                for (int j = 0; j < 4; j++) {                                   \
                    int rr = wn + j * 16 + r16;                                 \
                    int cc = (ks * 4 + q) ^ (rr & 7);                           \
                    b[j] = *(const short8*)&Bs[buf][rr * 64 + cc * 8];          \
                }                                                               \
                _Pragma("unroll")                                               \
                for (int i = 0; i < 4; i++)                                     \
                    _Pragma("unroll")                                           \
                    for (int j = 0; j < 4; j++)                                 \
                        acc[i][j] = __builtin_amdgcn_mfma_f32_16x16x32_bf16(    \
                            a[i], b[j], acc[i][j], 0, 0, 0);                    \
            }                                                                   \
        }

    STAGE128(0, 0);
    STAGE128(1, 1);
    VMCNT(8);
    BARM();
    int cur = 0;
    for (int kt = 0; kt < kIters - 2; kt++) {
        COMPUTE128(cur);
        BARM();
        STAGE128(cur, kt + 2);
        VMCNT(8);
        BARM();
        cur ^= 1;
    }
    COMPUTE128(cur);
    VMCNT(0);
    BARM();
    COMPUTE128(cur ^ 1);

    int m0 = tm * 128 + wm, n0 = tn * 128 + wn;
    #pragma unroll
    for (int i = 0; i < 4; i++) {
        int mm = m0 + i * 16 + q * 4;
        float rs[4];
        #pragma unroll
        for (int r = 0; r < 4; r++) rs[r] = (rowscale != nullptr) ? rowscale[mm + r] : 1.0f;
        #pragma unroll
        for (int j = 0; j < 4; j++) {
            int nn = n0 + j * 16 + r16;
            #pragma unroll
            for (int r = 0; r < 4; r++)
                C[(long)(mm + r) * ldc + nn] = acc[i][j][r] * rs[r];
        }
    }
    #undef STAGE128
    #undef COMPUTE128
}

extern "C" void kernel_launch(void* const* d_in, const int* in_sizes, int n_in,
                              void* d_out, int out_size, void* d_ws, size_t ws_size,
                              hipStream_t stream) {
    const float* x = (const float*)d_in[0];
    const float* wgt = (const float*)d_in[1];
    float* out = (float*)d_out;
    char* ws = (char*)d_ws;

    const size_t MB = 1048576;
    u16*   YT = (u16*)ws;                  // 16 MB  Y^T = (diag(sqrt r)x)^T [1024][8192]
    u16*   Yn = (u16*)(ws + 16 * MB);      // 16 MB  diag(r)x row-major [8192][1024]
    u16*   Wt = (u16*)(ws + 32 * MB);      //  2 MB  W^T bf16
    u16*   Gb = (u16*)(ws + 34 * MB);      //  2 MB  G bf16
    u16*   Mt = (u16*)(ws + 36 * MB);      //  2 MB  M^T bf16
    float* Gp = (float*)(ws + 38 * MB);    // 32 MB  8x4MB G partials
    // total 70 MB

    // 1) fused single-pass: row norms + Y^T + Yn (blocks 0..511) + W^T (512..767)
    prep_all<<<768, 256, 0, stream>>>(x, wgt, YT, Yn, Wt);
    // 2) G = Y^T·Y, upper-tri tiles (72 of 128 in 16x8 grid), split-K=8 -> Gp
    gemm64x128<<<dim3(72, 8), 256, 0, stream>>>(YT, YT, Gp, nullptr,
                                                8192, 8192, 1024, 8, 16, 1048576, 1, 0);
    // 3) Gb = bf16(sum Gp), mirroring the lower triangle (read-once)
    reduce_symC<<<256, 256, 0, stream>>>(Gp, Gb, 8, 1048576);
    // 4) M^T = W^T·G (G symmetric), no split-K, bf16 out -> Mt
    gemm64x128<<<dim3(128, 1), 256, 0, stream>>>(Wt, Gb, (float*)Mt, nullptr,
                                                 1024, 1024, 1024, 8, 16, 0, 0, 1);
    // 5) out = Yn·M  (M=8192, N=1024, K=1024, 512 blocks at 2/CU)
    gemm128<<<dim3(512, 1), 256, 0, stream>>>(Yn, Mt, out, nullptr,
                                              1024, 1024, 1024, 8, 16);
}